// Round 2
// baseline (220.287 us; speedup 1.0000x reference)
//
#include <hip/hip_runtime.h>
#include <hip/hip_bf16.h>
#include <stdint.h>

// LocalSlidingWindowAttention: B=2, T=2048, D=1024, H=16, hd=64, keys j in [i, i+64].
// Pipeline: dtype-detect -> canonicalize inputs to bf16 -> GEMM1 (qkv) -> attention -> GEMM2.
// GEMMs: m97-style 128x128 tile, BK=32, 4 waves, mfma_f32_16x16x32_bf16, global_load_lds w=16.
// GEMM2 epilogue emits bf16 or f32 per detected dtype (device flag; uniform branch).

typedef short bf16x8 __attribute__((ext_vector_type(8)));
typedef float f32x4 __attribute__((ext_vector_type(4)));

typedef const __attribute__((address_space(1))) void* gptr_t;
typedef __attribute__((address_space(3))) void* lptr_t;

__device__ __forceinline__ float bf2f(short u) {
    union { float f; uint32_t i; } x;
    x.i = ((uint32_t)(uint16_t)u) << 16;
    return x.f;
}
__device__ __forceinline__ short f2bf(float f) {
    __hip_bfloat16 h = __float2bfloat16(f);  // RNE
    return *reinterpret_cast<short*>(&h);
}

// Dtype sniffer: sample first 4096 half-words of w_qkv. True bf16 N(0,~0.03^2) data has
// exponent field in [100,140] for ~100% of half-words; f32 data's low halves are ~uniform
// mantissa bits (pass ~16%), so overall ~58%. Threshold 90%.
__global__ void detect_dtype(const unsigned short* __restrict__ w, int* __restrict__ flag) {
    __shared__ int cnt;
    if (threadIdx.x == 0) cnt = 0;
    __syncthreads();
    int c = 0;
#pragma unroll
    for (int j = 0; j < 16; ++j) {
        unsigned e = (w[threadIdx.x * 16 + j] >> 7) & 0xFF;
        c += (e >= 100 && e <= 140);
    }
    atomicAdd(&cnt, c);
    __syncthreads();
    if (threadIdx.x == 0) *flag = (cnt >= 3687) ? 1 : 0;  // 1 = bf16, 0 = f32
}

// Canonicalize: dst(bf16) <- src (bf16 copy or f32 convert), 8 elems/thread. n % 8 == 0.
__global__ void convert_to_bf16(const void* __restrict__ src, short* __restrict__ dst,
                                int n, const int* __restrict__ flag) {
    int i = (blockIdx.x * blockDim.x + threadIdx.x) * 8;
    if (i >= n) return;
    if (*flag) {
        *(uint4*)(dst + i) = *(const uint4*)((const short*)src + i);
    } else {
        const float* s = (const float*)src;
        short tmp[8];
#pragma unroll
        for (int j = 0; j < 8; ++j) tmp[j] = f2bf(s[i + j]);
        *(uint4*)(dst + i) = *(const uint4*)tmp;
    }
}

// C[m,n] = sum_k A[m,k]*Bt[n,k] + bias[n].  A: MxK, Bt: NxK row-major bf16.
// DUAL: epilogue writes bf16 if *flag else f32. M%128==0, N%128==0, K%32==0.
template <bool DUAL>
__global__ __launch_bounds__(256)
void gemm_bt_bias(const short* __restrict__ A, const short* __restrict__ Bt,
                  const short* __restrict__ bias, void* __restrict__ Cv,
                  int M, int N, int K, const int* __restrict__ flag) {
    __shared__ short As[128 * 32];  // unpadded: required by global_load_lds lane scatter
    __shared__ short Bs[128 * 32];

    const int tid  = threadIdx.x;
    const int lane = tid & 63;
    const int w    = tid >> 6;
    const int quad = lane >> 4;
    const int l16  = lane & 15;
    const int wm   = w >> 1;
    const int wn   = w & 1;
    const int mBase = blockIdx.y * 128;
    const int nBase = blockIdx.x * 128;

    f32x4 acc[4][4] = {};

    const int nK = K >> 5;
    for (int kt = 0; kt < nK; ++kt) {
        const int kb = kt << 5;
#pragma unroll
        for (int i = 0; i < 2; ++i) {
            const int e   = i * 2048 + tid * 8;        // flat elem in 128x32 tile
            const int row = e >> 5;
            const int col = e & 31;
            const short* ga = A  + (size_t)(mBase + row) * K + kb + col;
            const short* gb = Bt + (size_t)(nBase + row) * K + kb + col;
            lptr_t la = (lptr_t)(As + i * 2048 + w * 512);  // wave-uniform base + lane*16B
            lptr_t lb = (lptr_t)(Bs + i * 2048 + w * 512);
            __builtin_amdgcn_global_load_lds((gptr_t)ga, la, 16, 0, 0);
            __builtin_amdgcn_global_load_lds((gptr_t)gb, lb, 16, 0, 0);
        }
        __syncthreads();

        bf16x8 af[4], bfr[4];
#pragma unroll
        for (int mi = 0; mi < 4; ++mi)
            af[mi] = *(const bf16x8*)(As + (wm * 64 + mi * 16 + l16) * 32 + quad * 8);
#pragma unroll
        for (int ni = 0; ni < 4; ++ni)
            bfr[ni] = *(const bf16x8*)(Bs + (wn * 64 + ni * 16 + l16) * 32 + quad * 8);
#pragma unroll
        for (int mi = 0; mi < 4; ++mi)
#pragma unroll
            for (int ni = 0; ni < 4; ++ni)
                acc[mi][ni] = __builtin_amdgcn_mfma_f32_16x16x32_bf16(
                    af[mi], bfr[ni], acc[mi][ni], 0, 0, 0);
        __syncthreads();
    }

    // C/D layout: n = lane&15, m = quad*4 + r (m89/m91-verified).
    const bool obf = DUAL ? (*flag != 0) : true;
    if (obf) {
        short* C = (short*)Cv;
#pragma unroll
        for (int ni = 0; ni < 4; ++ni) {
            const int n = nBase + wn * 64 + ni * 16 + l16;
            const float bv = bf2f(bias[n]);
#pragma unroll
            for (int mi = 0; mi < 4; ++mi)
#pragma unroll
                for (int r = 0; r < 4; ++r) {
                    const int m = mBase + wm * 64 + mi * 16 + quad * 4 + r;
                    C[(size_t)m * N + n] = f2bf(acc[mi][ni][r] + bv);
                }
        }
    } else {
        float* C = (float*)Cv;
#pragma unroll
        for (int ni = 0; ni < 4; ++ni) {
            const int n = nBase + wn * 64 + ni * 16 + l16;
            const float bv = bf2f(bias[n]);
#pragma unroll
            for (int mi = 0; mi < 4; ++mi)
#pragma unroll
                for (int r = 0; r < 4; ++r) {
                    const int m = mBase + wm * 64 + mi * 16 + quad * 4 + r;
                    C[(size_t)m * N + n] = acc[mi][ni][r] + bv;
                }
        }
    }
}

// Attention: block = (32-query tile, head, batch), 256 threads = 4 waves, 8 queries/wave.
__global__ __launch_bounds__(256)
void attn_kernel(const short* __restrict__ qkv, short* __restrict__ attn_out,
                 int B, int T) {
    __shared__ float q_s[32 * 64];
    __shared__ short k_s[96 * 66];   // stride 66: per-lane-row dot reads are 2-way (free)
    __shared__ short v_s[96 * 64];
    __shared__ float p_s[4][72];

    const int tid  = threadIdx.x;
    const int lane = tid & 63;
    const int w    = tid >> 6;
    const int qs   = blockIdx.x * 32;
    const int h    = blockIdx.y;
    const int b    = blockIdx.z;
    const size_t rs   = 3 * 1024;
    const size_t base = (size_t)b * T * rs;
    const int qoff = h * 64, koff = 1024 + h * 64, voff = 2048 + h * 64;

    {
        const int row = tid >> 3, ch = (tid & 7) * 8;
        uint4 u = *(const uint4*)(qkv + base + (size_t)(qs + row) * rs + qoff + ch);
        const short* sp = (const short*)&u;
#pragma unroll
        for (int j = 0; j < 8; ++j) q_s[row * 64 + ch + j] = bf2f(sp[j]);
    }
#pragma unroll
    for (int i = 0; i < 3; ++i) {
        const int c = tid + i * 256;
        const int row = c >> 3, ch = (c & 7) * 8;
        int gr = qs + row; if (gr > T - 1) gr = T - 1;   // clamped; masked later
        uint4 uk = *(const uint4*)(qkv + base + (size_t)gr * rs + koff + ch);
        uint4 uv = *(const uint4*)(qkv + base + (size_t)gr * rs + voff + ch);
        const short* sk = (const short*)&uk;
#pragma unroll
        for (int j = 0; j < 8; ++j) k_s[row * 66 + ch + j] = sk[j];
        *(uint4*)&v_s[row * 64 + ch] = uv;
    }
    __syncthreads();

    const float scale = 0.125f;
    for (int s = 0; s < 8; ++s) {
        const int il = w * 8 + s;
        const int i  = qs + il;

        float sc = 0.f;
#pragma unroll
        for (int d = 0; d < 64; ++d)
            sc += q_s[il * 64 + d] * bf2f(k_s[(il + lane) * 66 + d]);
        const bool vl = (i + lane) < T;
        sc = vl ? sc * scale : -3.4e38f;

        float pp = q_s[il * 64 + lane] * bf2f(k_s[(il + 64) * 66 + lane]);
#pragma unroll
        for (int m = 32; m >= 1; m >>= 1) pp += __shfl_xor(pp, m);
        const bool v64 = (i + 64) < T;
        const float s64 = v64 ? pp * scale : -3.4e38f;

        float mx = sc;
#pragma unroll
        for (int m = 32; m >= 1; m >>= 1) mx = fmaxf(mx, __shfl_xor(mx, m));
        mx = fmaxf(mx, s64);
        const float p   = vl  ? __expf(sc  - mx) : 0.f;
        const float p64 = v64 ? __expf(s64 - mx) : 0.f;
        float sum = p;
#pragma unroll
        for (int m = 32; m >= 1; m >>= 1) sum += __shfl_xor(sum, m);
        sum += p64;
        const float inv = 1.0f / sum;   // sum >= 1: key o=0 always valid

        p_s[w][lane] = p;
        if (lane == 0) p_s[w][64] = p64;
        // same-wave LDS RAW -> compiler lgkmcnt wait; lockstep wave, no barrier needed

        float acc = 0.f;
#pragma unroll
        for (int o = 0; o < 65; ++o)
            acc += p_s[w][o] * bf2f(v_s[(il + o) * 64 + lane]);

        attn_out[((size_t)(b * T + i)) * 1024 + h * 64 + lane] = f2bf(acc * inv);
    }
}

extern "C" void kernel_launch(void* const* d_in, const int* in_sizes, int n_in,
                              void* d_out, int out_size, void* d_ws, size_t ws_size,
                              hipStream_t stream) {
    (void)in_sizes; (void)n_in; (void)out_size; (void)ws_size;
    const int B = 2, T = 2048, D = 1024;
    const int M = B * T;  // 4096

    char* ws = (char*)d_ws;
    int* flag = (int*)ws;
    size_t off = 256;
    short* xb   = (short*)(ws + off); off += (size_t)M * D * 2;       // 8.4 MB
    short* wqkb = (short*)(ws + off); off += (size_t)3 * D * D * 2;   // 6.3 MB
    short* bqkb = (short*)(ws + off); off += (size_t)3 * D * 2;
    short* wob  = (short*)(ws + off); off += (size_t)D * D * 2;       // 2.1 MB
    short* bob  = (short*)(ws + off); off += (size_t)D * 2;
    short* qkv  = (short*)(ws + off); off += (size_t)M * 3 * D * 2;   // 25.2 MB
    short* attn = (short*)(ws + off); off += (size_t)M * D * 2;       // 8.4 MB  (~50.4 MB total)

    detect_dtype<<<1, 256, 0, stream>>>((const unsigned short*)d_in[1], flag);

    auto cgrid = [](int n) { return dim3((n / 8 + 255) / 256); };
    convert_to_bf16<<<cgrid(M * D),     256, 0, stream>>>(d_in[0], xb,   M * D,     flag);
    convert_to_bf16<<<cgrid(3 * D * D), 256, 0, stream>>>(d_in[1], wqkb, 3 * D * D, flag);
    convert_to_bf16<<<cgrid(3 * D),     256, 0, stream>>>(d_in[2], bqkb, 3 * D,     flag);
    convert_to_bf16<<<cgrid(D * D),     256, 0, stream>>>(d_in[3], wob,  D * D,     flag);
    convert_to_bf16<<<cgrid(D),         256, 0, stream>>>(d_in[4], bob,  D,         flag);

    gemm_bt_bias<false><<<dim3(3 * D / 128, M / 128), 256, 0, stream>>>(
        xb, wqkb, bqkb, qkv, M, 3 * D, D, nullptr);
    attn_kernel<<<dim3(T / 32, 16, B), 256, 0, stream>>>(qkv, attn, B, T);
    gemm_bt_bias<true><<<dim3(D / 128, M / 128), 256, 0, stream>>>(
        attn, wob, bob, d_out, M, D, D, flag);
}

// Round 3
// 162.923 us; speedup vs baseline: 1.3521x; 1.3521x over previous
//
#include <hip/hip_runtime.h>
#include <hip/hip_bf16.h>
#include <stdint.h>

// LocalSlidingWindowAttention: B=2, T=2048, D=1024, H=16, hd=64, keys j in [i, i+64].
// f32 inputs/outputs (confirmed round 2). Pipeline:
//   convert_all (f32->bf16, one kernel) -> GEMM1 (qkv) -> MFMA attention -> GEMM2 (f32 out).
// GEMMs: m97-style 128x128 tile, BK=32, mfma_f32_16x16x32_bf16, global_load_lds w=16.
// Attention: 64 queries/block, per-wave 16-query mtile; QK^T 10 MFMAs (windowed 5 ntiles),
// softmax in C-layout regs, P->LDS (wave-private rows), PV 12 MFMAs.

typedef short bf16x8 __attribute__((ext_vector_type(8)));
typedef float f32x4 __attribute__((ext_vector_type(4)));

typedef const __attribute__((address_space(1))) void* gptr_t;
typedef __attribute__((address_space(3))) void* lptr_t;

__device__ __forceinline__ float bf2f(short u) {
    union { float f; uint32_t i; } x;
    x.i = ((uint32_t)(uint16_t)u) << 16;
    return x.f;
}
__device__ __forceinline__ short f2bf(float f) {
    __hip_bfloat16 h = __float2bfloat16(f);  // RNE
    return *reinterpret_cast<short*>(&h);
}

// One kernel converts all 5 f32 inputs to bf16. 8 elems/thread; segment select by flat idx.
// Boundaries (in 8-elem units): x 524288 | w_qkv 393216 | b_qkv 384 | w_out 131072 | b_out 128.
__global__ __launch_bounds__(256)
void convert_all(const float* __restrict__ x, const float* __restrict__ wq,
                 const float* __restrict__ bq, const float* __restrict__ wo,
                 const float* __restrict__ bo,
                 short* __restrict__ xb, short* __restrict__ wqb, short* __restrict__ bqb,
                 short* __restrict__ wob, short* __restrict__ bob) {
    int i = blockIdx.x * 256 + threadIdx.x;
    const float* src; short* dst; int o;
    if      (i <  524288) { src = x;  dst = xb;  o = i; }
    else if (i <  917504) { src = wq; dst = wqb; o = i - 524288; }
    else if (i <  917888) { src = bq; dst = bqb; o = i - 917504; }
    else if (i < 1048960) { src = wo; dst = wob; o = i - 917888; }
    else if (i < 1049088) { src = bo; dst = bob; o = i - 1048960; }
    else return;
    const int e = o * 8;
    float4 a = *(const float4*)(src + e);
    float4 b = *(const float4*)(src + e + 4);
    short t[8];
    t[0] = f2bf(a.x); t[1] = f2bf(a.y); t[2] = f2bf(a.z); t[3] = f2bf(a.w);
    t[4] = f2bf(b.x); t[5] = f2bf(b.y); t[6] = f2bf(b.z); t[7] = f2bf(b.w);
    *(uint4*)(dst + e) = *(const uint4*)t;
}

// C[m,n] = sum_k A[m,k]*Bt[n,k] + bias[n]. A: MxK, Bt: NxK row-major bf16.
// OUT_F32: write f32, else bf16. M%128==0, N%128==0, K%32==0.
template <bool OUT_F32>
__global__ __launch_bounds__(256)
void gemm_bt_bias(const short* __restrict__ A, const short* __restrict__ Bt,
                  const short* __restrict__ bias, void* __restrict__ Cv,
                  int M, int N, int K) {
    __shared__ short As[128 * 32];  // unpadded: required by global_load_lds lane layout
    __shared__ short Bs[128 * 32];

    const int tid  = threadIdx.x;
    const int lane = tid & 63;
    const int w    = tid >> 6;
    const int quad = lane >> 4;
    const int l16  = lane & 15;
    const int wm   = w >> 1;
    const int wn   = w & 1;
    const int mBase = blockIdx.y * 128;
    const int nBase = blockIdx.x * 128;

    f32x4 acc[4][4] = {};

    const int nK = K >> 5;
    for (int kt = 0; kt < nK; ++kt) {
        const int kb = kt << 5;
#pragma unroll
        for (int i = 0; i < 2; ++i) {
            const int e   = i * 2048 + tid * 8;
            const int row = e >> 5;
            const int col = e & 31;
            const short* ga = A  + (size_t)(mBase + row) * K + kb + col;
            const short* gb = Bt + (size_t)(nBase + row) * K + kb + col;
            lptr_t la = (lptr_t)(As + i * 2048 + w * 512);
            lptr_t lb = (lptr_t)(Bs + i * 2048 + w * 512);
            __builtin_amdgcn_global_load_lds((gptr_t)ga, la, 16, 0, 0);
            __builtin_amdgcn_global_load_lds((gptr_t)gb, lb, 16, 0, 0);
        }
        __syncthreads();

        bf16x8 af[4], bfr[4];
#pragma unroll
        for (int mi = 0; mi < 4; ++mi)
            af[mi] = *(const bf16x8*)(As + (wm * 64 + mi * 16 + l16) * 32 + quad * 8);
#pragma unroll
        for (int ni = 0; ni < 4; ++ni)
            bfr[ni] = *(const bf16x8*)(Bs + (wn * 64 + ni * 16 + l16) * 32 + quad * 8);
#pragma unroll
        for (int mi = 0; mi < 4; ++mi)
#pragma unroll
            for (int ni = 0; ni < 4; ++ni)
                acc[mi][ni] = __builtin_amdgcn_mfma_f32_16x16x32_bf16(
                    af[mi], bfr[ni], acc[mi][ni], 0, 0, 0);
        __syncthreads();
    }

    // C/D layout: n = lane&15, m = quad*4 + r.
#pragma unroll
    for (int ni = 0; ni < 4; ++ni) {
        const int n = nBase + wn * 64 + ni * 16 + l16;
        const float bv = bf2f(bias[n]);
#pragma unroll
        for (int mi = 0; mi < 4; ++mi)
#pragma unroll
            for (int r = 0; r < 4; ++r) {
                const int m = mBase + wm * 64 + mi * 16 + quad * 4 + r;
                if (OUT_F32) ((float*)Cv)[(size_t)m * N + n] = acc[mi][ni][r] + bv;
                else         ((short*)Cv)[(size_t)m * N + n] = f2bf(acc[mi][ni][r] + bv);
            }
    }
}

// MFMA attention. Block = 64 queries x 1 head x 1 batch; 256 thr = 4 waves.
// Wave w owns queries [qs+16w, qs+16w+16). Its key window: local keys [16w, 16w+80).
__global__ __launch_bounds__(256)
void attn_mfma(const short* __restrict__ qkv, short* __restrict__ attn_out, int B, int T) {
    __shared__ short k_s[128 * 72];   // stride 72: b128 frag reads 2-way (free)
    __shared__ short v_s[144 * 66];   // stride 66: scalar B-frag reads full-spread (free)
    __shared__ short p_s[64 * 104];   // wave-private rows; wave-relative cols [0,96)

    const int tid  = threadIdx.x;
    const int lane = tid & 63;
    const int w    = tid >> 6;
    const int qd   = lane >> 4;       // quad 0..3
    const int l16  = lane & 15;
    const int qs   = blockIdx.x * 64;
    const int h    = blockIdx.y;
    const int b    = blockIdx.z;
    const size_t rs   = 3072;
    const size_t base = (size_t)b * T * rs;
    const int qoff = h * 64, koff = 1024 + h * 64, voff = 2048 + h * 64;

    // Stage K rows [0,128) and V rows [0,144) (clamped at T-1; masked later).
#pragma unroll
    for (int i = 0; i < 5; ++i) {
        const int c   = tid + i * 256;
        const int row = c >> 3;
        if (row >= 144) break;
        const int ch = (c & 7) * 8;
        int gr = qs + row; if (gr > T - 1) gr = T - 1;
        uint4 uv = *(const uint4*)(qkv + base + (size_t)gr * rs + voff + ch);
        if (row < 128) {
            uint4 uk = *(const uint4*)(qkv + base + (size_t)gr * rs + koff + ch);
            *(uint4*)&k_s[row * 72 + ch] = uk;
        }
        const uint32_t* vp = (const uint32_t*)&uv;
        uint32_t* vd = (uint32_t*)&v_s[row * 66 + ch];  // 4x b32: stride-66 rows
        vd[0] = vp[0]; vd[1] = vp[1]; vd[2] = vp[2]; vd[3] = vp[3];
    }
    __syncthreads();

    // Q A-fragments straight from global (rows qs+16w+l16 always < T).
    bf16x8 aq0, aq1;
    {
        const short* g = qkv + base + (size_t)(qs + 16 * w + l16) * rs + qoff + qd * 8;
        aq0 = *(const bf16x8*)(g);
        aq1 = *(const bf16x8*)(g + 32);
    }

    // QK^T: 5 key ntiles x 2 ksteps.
    f32x4 sacc[5] = {};
#pragma unroll
    for (int u = 0; u < 5; ++u) {
        const int krow = 16 * (w + u) + l16;     // <= 127
        bf16x8 bk0 = *(const bf16x8*)&k_s[krow * 72 + qd * 8];
        bf16x8 bk1 = *(const bf16x8*)&k_s[krow * 72 + 32 + qd * 8];
        sacc[u] = __builtin_amdgcn_mfma_f32_16x16x32_bf16(aq0, bk0, sacc[u], 0, 0, 0);
        sacc[u] = __builtin_amdgcn_mfma_f32_16x16x32_bf16(aq1, bk1, sacc[u], 0, 0, 0);
    }

    // Masked softmax per row m = 4*qd + r (lane group = same qd, 16 l16 lanes).
    const float scale = 0.125f;
    float pw[5][4];
    float inv[4];
#pragma unroll
    for (int r = 0; r < 4; ++r) {
        const int m = 4 * qd + r;
        float mx = -3.4e38f;
#pragma unroll
        for (int u = 0; u < 5; ++u) {
            const int rel = 16 * u + l16 - m;                 // j - i
            const int j   = qs + 16 * (w + u) + l16;
            const bool ok = (rel >= 0) & (rel <= 64) & (j < T);
            const float v = ok ? sacc[u][r] * scale : -3.4e38f;
            pw[u][r] = v;
            mx = fmaxf(mx, v);
        }
#pragma unroll
        for (int msk = 1; msk <= 8; msk <<= 1) mx = fmaxf(mx, __shfl_xor(mx, msk));
        float sum = 0.f;
#pragma unroll
        for (int u = 0; u < 5; ++u) {
            float e = (pw[u][r] <= -3.0e38f) ? 0.f : __expf(pw[u][r] - mx);
            pw[u][r] = e;
            sum += e;
        }
#pragma unroll
        for (int msk = 1; msk <= 8; msk <<= 1) sum += __shfl_xor(sum, msk);
        inv[r] = 1.0f / sum;    // >= exp(0) contribution: row always has rel==0 valid
    }

    // P -> LDS (bf16), wave-private rows 16w+m, wave-relative cols 16u+l16; zero tile u=5.
#pragma unroll
    for (int u = 0; u < 5; ++u)
#pragma unroll
        for (int r = 0; r < 4; ++r)
            p_s[(16 * w + 4 * qd + r) * 104 + 16 * u + l16] = f2bf(pw[u][r]);
#pragma unroll
    for (int r = 0; r < 4; ++r)
        p_s[(16 * w + 4 * qd + r) * 104 + 80 + l16] = 0;
    // wave-private rows; same-wave RAW -> lgkmcnt wait, no barrier needed

    // PV: 3 ksteps x 4 d-tiles. A = P rows (b128); B = V columns (8x ds_read_u16, free).
    f32x4 oacc[4] = {};
#pragma unroll
    for (int ks = 0; ks < 3; ++ks) {
        bf16x8 ap = *(const bf16x8*)&p_s[(16 * w + l16) * 104 + ks * 32 + qd * 8];
#pragma unroll
        for (int dt = 0; dt < 4; ++dt) {
            short t[8];
#pragma unroll
            for (int j = 0; j < 8; ++j)
                t[j] = v_s[(16 * w + ks * 32 + qd * 8 + j) * 66 + 16 * dt + l16];
            bf16x8 bv = *(const bf16x8*)t;
            oacc[dt] = __builtin_amdgcn_mfma_f32_16x16x32_bf16(ap, bv, oacc[dt], 0, 0, 0);
        }
    }

    // Store O (C-layout: row 4qd+r, col 16dt+l16), normalized by inv[r].
#pragma unroll
    for (int dt = 0; dt < 4; ++dt)
#pragma unroll
        for (int r = 0; r < 4; ++r) {
            const size_t row = (size_t)(b * T + qs + 16 * w + 4 * qd + r);
            attn_out[row * 1024 + h * 64 + 16 * dt + l16] = f2bf(oacc[dt][r] * inv[r]);
        }
}

extern "C" void kernel_launch(void* const* d_in, const int* in_sizes, int n_in,
                              void* d_out, int out_size, void* d_ws, size_t ws_size,
                              hipStream_t stream) {
    (void)in_sizes; (void)n_in; (void)out_size; (void)ws_size;
    const int B = 2, T = 2048, D = 1024;
    const int M = B * T;  // 4096

    char* ws = (char*)d_ws;
    size_t off = 0;
    short* xb   = (short*)(ws + off); off += (size_t)M * D * 2;
    short* wqkb = (short*)(ws + off); off += (size_t)3 * D * D * 2;
    short* bqkb = (short*)(ws + off); off += (size_t)3 * D * 2;
    short* wob  = (short*)(ws + off); off += (size_t)D * D * 2;
    short* bob  = (short*)(ws + off); off += (size_t)D * 2;
    short* qkv  = (short*)(ws + off); off += (size_t)M * 3 * D * 2;
    short* attn = (short*)(ws + off); off += (size_t)M * D * 2;

    convert_all<<<dim3(4099), 256, 0, stream>>>(
        (const float*)d_in[0], (const float*)d_in[1], (const float*)d_in[2],
        (const float*)d_in[3], (const float*)d_in[4], xb, wqkb, bqkb, wob, bob);

    gemm_bt_bias<false><<<dim3(3 * D / 128, M / 128), 256, 0, stream>>>(
        xb, wqkb, bqkb, qkv, M, 3 * D, D);
    attn_mfma<<<dim3(T / 64, 16, B), 256, 0, stream>>>(qkv, attn, B, T);
    gemm_bt_bias<true><<<dim3(D / 128, M / 128), 256, 0, stream>>>(
        attn, wob, bob, d_out, M, D, D);
}